// Round 23
// baseline (454.108 us; speedup 1.0000x reference)
//
#include <hip/hip_runtime.h>
#include <math.h>

#define HGT 100
#define WID 100
#define S_TOK (HGT * WID)          // 10000
#define D_MODEL 256
#define N_HEADS 8
#define DH 32
#define N_POINTS 4
#define N_LAYERS 6
#define BS 2
#define M_TOK (BS * S_TOK)         // 20000

typedef __attribute__((ext_vector_type(8))) short short8v;   // 8 bf16 = 16 B
typedef __attribute__((ext_vector_type(4))) short short4v;   // 4 bf16 = 8 B
typedef __attribute__((ext_vector_type(4))) float f32x4;

__device__ __forceinline__ short f2bf(float f) {
  union { float f; unsigned u; } v; v.f = f;
  unsigned r = v.u + 0x7fff + ((v.u >> 16) & 1);   // round-to-nearest-even
  return (short)(r >> 16);
}
__device__ __forceinline__ float bf2f(short s) {
  union { unsigned u; float f; } v;
  v.u = ((unsigned)(unsigned short)s) << 16;
  return v.f;
}

// async global -> LDS, 16 B per lane. lds dest = wave-uniform base + lane*16.
__device__ __forceinline__ void gld16(const short* g, short* l) {
  __builtin_amdgcn_global_load_lds(
      (const __attribute__((address_space(1))) unsigned int*)g,
      (__attribute__((address_space(3))) unsigned int*)l, 16, 0, 0);
}

// ---------------------------------------------------------------------------
// Fused token prep: transpose [bs,C,S]->[bs,S,C] for features AND pos; emit
// posb bf16 (pos+level), srcb bf16(features), qb bf16(src+posb).
// grid (313, 8, 2) block (32,8)
// ---------------------------------------------------------------------------
__global__ __launch_bounds__(256) void prep_tokens(
    const float* __restrict__ feat, const float* __restrict__ posin,
    const float* __restrict__ level, short* __restrict__ posb,
    short* __restrict__ srcb, short* __restrict__ qb) {
  __shared__ float tf[32][33];
  __shared__ float tp[32][33];
  int b = blockIdx.z;
  int s0 = blockIdx.x * 32;
  int c0 = blockIdx.y * 32;
  int tx = threadIdx.x, ty = threadIdx.y;
#pragma unroll
  for (int i = 0; i < 4; ++i) {
    int c = c0 + ty + i * 8;
    int s = s0 + tx;
    bool ok = s < S_TOK;
    size_t o = ((size_t)b * D_MODEL + c) * S_TOK + s;
    tf[ty + i * 8][tx] = ok ? feat[o] : 0.f;
    tp[ty + i * 8][tx] = ok ? posin[o] : 0.f;
  }
  __syncthreads();
#pragma unroll
  for (int i = 0; i < 4; ++i) {
    int s = s0 + ty + i * 8;
    int c = c0 + tx;
    if (s < S_TOK) {
      float f = tf[tx][ty + i * 8];
      float p = tp[tx][ty + i * 8] + level[c];
      size_t o = ((size_t)b * S_TOK + s) * D_MODEL + c;
      short pb = f2bf(p);
      posb[o] = pb;
      srcb[o] = f2bf(f);
      qb[o] = f2bf(f + bf2f(pb));
    }
  }
}

// ---------------------------------------------------------------------------
// Fused weight prep: transpose + fp32->bf16 + XOR pre-swizzle.
// Dst element (n, k) stored at col (k&~63) | ((((k>>3)&7) ^ (n&7))<<3) | (k&7)
// so that a LINEAR 16B/lane copy into LDS yields LDS(row,s)=logical(row,
// s^(row&7)).  grid (8, 8, 36): z = l*6+widx; widx 0..3: 256-col weights;
// 4: off (64 rows of woa); 5: aw (rows 64..95 of woa; woa padded to 128).
// ---------------------------------------------------------------------------
__global__ __launch_bounds__(256) void prep_weights(
    const float* __restrict__ val_w, const float* __restrict__ out_w,
    const float* __restrict__ ffn_w1, const float* __restrict__ ffn_w2,
    const float* __restrict__ off_w, const float* __restrict__ aw_w,
    short* __restrict__ wv, short* __restrict__ wo, short* __restrict__ w1t,
    short* __restrict__ w2t, short* __restrict__ woa) {
  int z = blockIdx.z;
  int l = z / 6, widx = z - (z / 6) * 6;
  const float* s;
  short* d;
  int N;
  if (widx == 0)      { s = val_w  + (size_t)l * 65536; d = wv  + (size_t)l * 65536; N = 256; }
  else if (widx == 1) { s = out_w  + (size_t)l * 65536; d = wo  + (size_t)l * 65536; N = 256; }
  else if (widx == 2) { s = ffn_w1 + (size_t)l * 65536; d = w1t + (size_t)l * 65536; N = 256; }
  else if (widx == 3) { s = ffn_w2 + (size_t)l * 65536; d = w2t + (size_t)l * 65536; N = 256; }
  else if (widx == 4) { s = off_w + (size_t)l * 256 * 64; d = woa + (size_t)l * 32768; N = 64; }
  else                { s = aw_w  + (size_t)l * 256 * 32; d = woa + (size_t)l * 32768 + (size_t)64 * 256; N = 32; }
  int n0 = blockIdx.x * 32, k0 = blockIdx.y * 32;
  if (n0 >= N) return;
  __shared__ float t[32][33];
  int tx = threadIdx.x, ty = threadIdx.y;
#pragma unroll
  for (int i = 0; i < 4; ++i) {
    int k = k0 + ty + i * 8;
    int n = n0 + tx;
    t[ty + i * 8][tx] = (n < N) ? s[(size_t)k * N + n] : 0.f;
  }
  __syncthreads();
#pragma unroll
  for (int i = 0; i < 4; ++i) {
    int n = n0 + ty + i * 8;
    int k = k0 + tx;
    if (n < N) {
      int slot = ((k >> 3) & 7) ^ (n & 7);   // (64+n)&7 == n&7 for widx5
      size_t dk = (size_t)(k & ~63) + (slot << 3) + (k & 7);
      d[(size_t)n * 256 + dk] = f2bf(t[tx][ty + i * 8]);
    }
  }
}

__global__ void biascat_kernel(const float* __restrict__ ob,
                               const float* __restrict__ ab,
                               float* __restrict__ dst) {
  int l = blockIdx.x, i = threadIdx.x;
  dst[l * 96 + i] = (i < 64) ? ob[l * 64 + i] : ab[l * 32 + (i - 64)];
}

// ---------------------------------------------------------------------------
// Merged value-proj + offset/logit GEMM dispatch. Grid 626 x 512 thr.
// Double-buffered gload_lds staging (1 barrier / K-tile, latency hidden
// under MFMA). Blocks 0..312 (role A): value = bf16(srcb@WV^T + vb) [N=256]
// Blocks 313..625 (role B): offaw = f32(qb@WOA^T + bias96) [N=96; woa 128r]
// ---------------------------------------------------------------------------
__global__ __launch_bounds__(512) void gemm_vq(
    const short* __restrict__ srcb, const short* __restrict__ qb,
    const short* __restrict__ WV, const short* __restrict__ WOA,
    const float* __restrict__ vb, const float* __restrict__ b96,
    short* __restrict__ value, float* __restrict__ offaw) {
  __shared__ __align__(16) short As[2][64 * 64];     // 16 KB
  __shared__ __align__(16) short Bs[2][256 * 64];    // 64 KB
  int tid = threadIdx.x;
  int wave = tid >> 6, lane = tid & 63;
  int lr = lane & 15, kb = lane >> 4;
  int bx = blockIdx.x;
  int sc16 = (lane & 7) ^ ((lane >> 3) & 7);   // A source slot involution
  int r7 = lr & 7;
  int sl0 = (kb ^ r7) << 3;                    // ks=0 read slot*8
  int sl1 = ((4 + kb) ^ r7) << 3;              // ks=1

  if (bx < 313) {
    // ---------------- role A: value projection (N=256) ----------------
    int wr = wave >> 2, wc = wave & 3;
    int bm = bx * 64;
    int arow = bm + wave * 8 + (lane >> 3);
    if (arow >= M_TOK) arow = M_TOK - 1;       // tail rows discarded later
    const short* aS = srcb + (size_t)arow * 256 + sc16 * 8;
    const short* bS = WV + (size_t)(wave * 32 + (lane >> 3)) * 256 + (lane & 7) * 8;
    int aOff = wave * 512;
    int bOff = wave * 32 * 64;

    f32x4 acc[2][4] = {};
    // prologue: stage tile 0 into buffer 0
    gld16(aS, As[0] + aOff);
#pragma unroll
    for (int c = 0; c < 4; ++c)
      gld16(bS + (size_t)(c * 8) * 256, Bs[0] + bOff + c * 8 * 64);
    __syncthreads();
    int cur = 0;
    for (int k0 = 0; k0 < 256; k0 += 64) {
      int nxt = cur ^ 1;
      if (k0 < 192) {                          // issue next-tile loads
        gld16(aS + k0 + 64, As[nxt] + aOff);
#pragma unroll
        for (int c = 0; c < 4; ++c)
          gld16(bS + (size_t)(c * 8) * 256 + k0 + 64,
                Bs[nxt] + bOff + c * 8 * 64);
      }
#pragma unroll
      for (int ks = 0; ks < 2; ++ks) {
        int sl = ks ? sl1 : sl0;
        short8v af[2], bf[4];
#pragma unroll
        for (int i = 0; i < 2; ++i)
          af[i] = *reinterpret_cast<const short8v*>(
              &As[cur][(wr * 32 + i * 16 + lr) * 64 + sl]);
#pragma unroll
        for (int j = 0; j < 4; ++j)
          bf[j] = *reinterpret_cast<const short8v*>(
              &Bs[cur][(wc * 64 + j * 16 + lr) * 64 + sl]);
#pragma unroll
        for (int i = 0; i < 2; ++i)
#pragma unroll
          for (int j = 0; j < 4; ++j)
            acc[i][j] = __builtin_amdgcn_mfma_f32_16x16x32_bf16(
                af[i], bf[j], acc[i][j], 0, 0, 0);
      }
      __syncthreads();   // drains vmcnt (next buf ready) + reads of cur done
      cur = nxt;
    }
    float bb[4];
#pragma unroll
    for (int fn = 0; fn < 4; ++fn) bb[fn] = vb[wc * 64 + fn * 16 + lr];
#pragma unroll
    for (int fm = 0; fm < 2; ++fm)
#pragma unroll
      for (int i = 0; i < 4; ++i) {
        int r = bm + wr * 32 + fm * 16 + kb * 4 + i;
        if (r >= M_TOK) continue;
#pragma unroll
        for (int fn = 0; fn < 4; ++fn) {
          int c = wc * 64 + fn * 16 + lr;
          value[(size_t)r * 256 + c] = f2bf(acc[fm][fn][i] + bb[fn]);
        }
      }
  } else {
    // ---------------- role B: offsets + logits (N=96, 128 staged) ------
    int wr = wave >> 2, wc = wave & 3;         // 2 x 4 waves, tile 32x32
    int bm = (bx - 313) * 64;
    int arow = bm + wave * 8 + (lane >> 3);
    if (arow >= M_TOK) arow = M_TOK - 1;
    const short* aS = qb + (size_t)arow * 256 + sc16 * 8;
    const short* bS = WOA + (size_t)(wave * 16 + (lane >> 3)) * 256 + (lane & 7) * 8;
    int aOff = wave * 512;
    int bOff = wave * 16 * 64;

    f32x4 acc[2][2] = {};
    gld16(aS, As[0] + aOff);
#pragma unroll
    for (int c = 0; c < 2; ++c)
      gld16(bS + (size_t)(c * 8) * 256, Bs[0] + bOff + c * 8 * 64);
    __syncthreads();
    int cur = 0;
    for (int k0 = 0; k0 < 256; k0 += 64) {
      int nxt = cur ^ 1;
      if (k0 < 192) {
        gld16(aS + k0 + 64, As[nxt] + aOff);
#pragma unroll
        for (int c = 0; c < 2; ++c)
          gld16(bS + (size_t)(c * 8) * 256 + k0 + 64,
                Bs[nxt] + bOff + c * 8 * 64);
      }
#pragma unroll
      for (int ks = 0; ks < 2; ++ks) {
        int sl = ks ? sl1 : sl0;
        short8v af[2], bf[2];
#pragma unroll
        for (int i = 0; i < 2; ++i)
          af[i] = *reinterpret_cast<const short8v*>(
              &As[cur][(wr * 32 + i * 16 + lr) * 64 + sl]);
#pragma unroll
        for (int j = 0; j < 2; ++j)
          bf[j] = *reinterpret_cast<const short8v*>(
              &Bs[cur][(wc * 32 + j * 16 + lr) * 64 + sl]);
#pragma unroll
        for (int i = 0; i < 2; ++i)
#pragma unroll
          for (int j = 0; j < 2; ++j)
            acc[i][j] = __builtin_amdgcn_mfma_f32_16x16x32_bf16(
                af[i], bf[j], acc[i][j], 0, 0, 0);
      }
      __syncthreads();
      cur = nxt;
    }
#pragma unroll
    for (int fn = 0; fn < 2; ++fn) {
      int c = wc * 32 + fn * 16 + lr;
      if (c >= 96) continue;
      float bv = b96[c];
#pragma unroll
      for (int fm = 0; fm < 2; ++fm)
#pragma unroll
        for (int i = 0; i < 4; ++i) {
          int r = bm + wr * 32 + fm * 16 + kb * 4 + i;
          if (r < M_TOK) offaw[(size_t)r * 96 + c] = acc[fm][fn][i] + bv;
        }
    }
  }
}

// ---------------------------------------------------------------------------
// Out-proj + residual + LN1. BM=64, 512 thr = 8 waves (2x4), wave 32x64.
// Grid 313. Double-buffered gload_lds staging. resid in-place (bf16).
// ---------------------------------------------------------------------------
__global__ __launch_bounds__(512) void gemm_out_ln1(
    const short* __restrict__ A, const short* __restrict__ WT,
    const float* __restrict__ bias, short* __restrict__ resid,
    const float* __restrict__ g, const float* __restrict__ lnb) {
  __shared__ __align__(16) short As[2][64 * 64];
  __shared__ __align__(16) short Bs[2][256 * 64];
  int tid = threadIdx.x;
  int wave = tid >> 6, lane = tid & 63;
  int lr = lane & 15, kb = lane >> 4;
  int wr = wave >> 2, wc = wave & 3;
  int bm = blockIdx.x * 64;
  int sc16 = (lane & 7) ^ ((lane >> 3) & 7);
  int r7 = lr & 7;
  int sl0 = (kb ^ r7) << 3;
  int sl1 = ((4 + kb) ^ r7) << 3;

  int arow = bm + wave * 8 + (lane >> 3);
  if (arow >= M_TOK) arow = M_TOK - 1;
  const short* aS = A + (size_t)arow * 256 + sc16 * 8;
  const short* bS = WT + (size_t)(wave * 32 + (lane >> 3)) * 256 + (lane & 7) * 8;
  int aOff = wave * 512;
  int bOff = wave * 32 * 64;

  f32x4 acc[2][4] = {};

  gld16(aS, As[0] + aOff);
#pragma unroll
  for (int c = 0; c < 4; ++c)
    gld16(bS + (size_t)(c * 8) * 256, Bs[0] + bOff + c * 8 * 64);
  __syncthreads();
  int cur = 0;
  for (int k0 = 0; k0 < 256; k0 += 64) {
    int nxt = cur ^ 1;
    if (k0 < 192) {
      gld16(aS + k0 + 64, As[nxt] + aOff);
#pragma unroll
      for (int c = 0; c < 4; ++c)
        gld16(bS + (size_t)(c * 8) * 256 + k0 + 64,
              Bs[nxt] + bOff + c * 8 * 64);
    }
#pragma unroll
    for (int ks = 0; ks < 2; ++ks) {
      int sl = ks ? sl1 : sl0;
      short8v af[2], bf[4];
#pragma unroll
      for (int i = 0; i < 2; ++i)
        af[i] = *reinterpret_cast<const short8v*>(
            &As[cur][(wr * 32 + i * 16 + lr) * 64 + sl]);
#pragma unroll
      for (int j = 0; j < 4; ++j)
        bf[j] = *reinterpret_cast<const short8v*>(
            &Bs[cur][(wc * 64 + j * 16 + lr) * 64 + sl]);
#pragma unroll
      for (int i = 0; i < 2; ++i)
#pragma unroll
        for (int j = 0; j < 4; ++j)
          acc[i][j] = __builtin_amdgcn_mfma_f32_16x16x32_bf16(af[i], bf[j],
                                                              acc[i][j], 0, 0, 0);
    }
    __syncthreads();
    cur = nxt;
  }

  float bb[4];
#pragma unroll
  for (int fn = 0; fn < 4; ++fn) bb[fn] = bias[wc * 64 + fn * 16 + lr];

  // ---- fused residual (bf16) + LayerNorm epilogue ----
  float* lns = (float*)As;           // [64][4] row partial sums
  float* lnq = lns + 256;            // [64][4] row partial sumsq
  float mean_[2][4], rs_[2][4];
#pragma unroll
  for (int fm = 0; fm < 2; ++fm)
#pragma unroll
    for (int i = 0; i < 4; ++i) {
      int lrow = wr * 32 + fm * 16 + kb * 4 + i;
      int r = bm + lrow;
      bool ok = r < M_TOK;
      float s = 0.f, q = 0.f;
#pragma unroll
      for (int fn = 0; fn < 4; ++fn) {
        int c = wc * 64 + fn * 16 + lr;
        float v = acc[fm][fn][i] + bb[fn];
        if (ok) v += bf2f(resid[(size_t)r * 256 + c]);
        acc[fm][fn][i] = v;
        s += v; q += v * v;
      }
#pragma unroll
      for (int o = 1; o < 16; o <<= 1) {
        s += __shfl_xor(s, o);
        q += __shfl_xor(q, o);
      }
      if (lr == 0) { lns[lrow * 4 + wc] = s; lnq[lrow * 4 + wc] = q; }
    }
  __syncthreads();
#pragma unroll
  for (int fm = 0; fm < 2; ++fm)
#pragma unroll
    for (int i = 0; i < 4; ++i) {
      int lrow = wr * 32 + fm * 16 + kb * 4 + i;
      float S = lns[lrow * 4 + 0] + lns[lrow * 4 + 1] + lns[lrow * 4 + 2] +
                lns[lrow * 4 + 3];
      float Q = lnq[lrow * 4 + 0] + lnq[lrow * 4 + 1] + lnq[lrow * 4 + 2] +
                lnq[lrow * 4 + 3];
      float mean = S * (1.f / 256.f);
      float var = Q * (1.f / 256.f) - mean * mean;
      mean_[fm][i] = mean;
      rs_[fm][i] = rsqrtf(var + 1e-5f);
    }
  float g4[4], lb4[4];
#pragma unroll
  for (int fn = 0; fn < 4; ++fn) {
    int c = wc * 64 + fn * 16 + lr;
    g4[fn] = g[c]; lb4[fn] = lnb[c];
  }
#pragma unroll
  for (int fm = 0; fm < 2; ++fm)
#pragma unroll
    for (int i = 0; i < 4; ++i) {
      int r = bm + wr * 32 + fm * 16 + kb * 4 + i;
      if (r >= M_TOK) continue;
#pragma unroll
      for (int fn = 0; fn < 4; ++fn) {
        int c = wc * 64 + fn * 16 + lr;
        float o = (acc[fm][fn][i] - mean_[fm][i]) * rs_[fm][i] * g4[fn] + lb4[fn];
        resid[(size_t)r * 256 + c] = f2bf(o);
      }
    }
}

// ---------------------------------------------------------------------------
// Fused FFN: H = relu(A@W1^T+b1) in LDS, then LN(resid + H@W2^T+b2).
// gload_lds for A and both weight tiles; Hs keeps padded (264) layout.
// BM=64, 512 thr = 8 waves (2x4), wave tile 32x64. Grid: 313.
// MODE 2: -> resid bf16 in-place + qb = bf16(out+posb).
// MODE 3: -> outf f32 only (final layer).  (single-buffered; R22 body)
// ---------------------------------------------------------------------------
template <int MODE>
__global__ __launch_bounds__(512) void gemm_ffn_ln3(
    const short* __restrict__ A, const short* __restrict__ W1T,
    const float* __restrict__ b1, const short* __restrict__ W2T,
    const float* __restrict__ b2, short* __restrict__ resid,
    float* __restrict__ outf, short* __restrict__ qb,
    const short* __restrict__ posb, const float* __restrict__ g,
    const float* __restrict__ lnb) {
  __shared__ __align__(16) short As[64 * 64];
  __shared__ __align__(16) short Bs[256 * 64];
  __shared__ __align__(16) short Hs[64 * 264];   // hidden, pad 264
  int tid = threadIdx.x;
  int wave = tid >> 6, lane = tid & 63;
  int lr = lane & 15, kb = lane >> 4;
  int wr = wave >> 2, wc = wave & 3;
  int bm = blockIdx.x * 64;
  int sc16 = (lane & 7) ^ ((lane >> 3) & 7);
  int r7 = lr & 7;
  int sl0 = (kb ^ r7) << 3;
  int sl1 = ((4 + kb) ^ r7) << 3;

  int arow = bm + wave * 8 + (lane >> 3);
  if (arow >= M_TOK) arow = M_TOK - 1;
  const short* aS = A + (size_t)arow * 256 + sc16 * 8;
  short* aD = As + wave * 512;
  short* bD = Bs + wave * 32 * 64;
  int brow0 = wave * 32 + (lane >> 3);
  int bcol = (lane & 7) * 8;

  f32x4 acc[2][4] = {};

  // ---- phase 1: H = relu(A@W1^T + b1) ----
  {
    const short* bS = W1T + (size_t)brow0 * 256 + bcol;
    for (int k0 = 0; k0 < 256; k0 += 64) {
      gld16(aS + k0, aD);
#pragma unroll
      for (int c = 0; c < 4; ++c)
        gld16(bS + (size_t)(c * 8) * 256 + k0, bD + c * 8 * 64);
      __syncthreads();
#pragma unroll
      for (int ks = 0; ks < 2; ++ks) {
        int sl = ks ? sl1 : sl0;
        short8v af[2], bf[4];
#pragma unroll
        for (int i = 0; i < 2; ++i)
          af[i] = *reinterpret_cast<const short8v*>(
              &As[(wr * 32 + i * 16 + lr) * 64 + sl]);
#pragma unroll
        for (int j = 0; j < 4; ++j)
          bf[j] = *reinterpret_cast<const short8v*>(
              &Bs[(wc * 64 + j * 16 + lr) * 64 + sl]);
#pragma unroll
        for (int i = 0; i < 2; ++i)
#pragma unroll
          for (int j = 0; j < 4; ++j)
            acc[i][j] = __builtin_amdgcn_mfma_f32_16x16x32_bf16(
                af[i], bf[j], acc[i][j], 0, 0, 0);
      }
      __syncthreads();
    }
    float bb1[4];
#pragma unroll
    for (int fn = 0; fn < 4; ++fn) bb1[fn] = b1[wc * 64 + fn * 16 + lr];
#pragma unroll
    for (int fm = 0; fm < 2; ++fm)
#pragma unroll
      for (int i = 0; i < 4; ++i) {
        int lrow = wr * 32 + fm * 16 + kb * 4 + i;
#pragma unroll
        for (int fn = 0; fn < 4; ++fn) {
          int c = wc * 64 + fn * 16 + lr;
          float v = fmaxf(acc[fm][fn][i] + bb1[fn], 0.f);
          Hs[lrow * 264 + c] = f2bf(v);
        }
      }
  }

  // ---- phase 2: LN(resid + H@W2^T + b2); A from Hs (plain layout) ----
#pragma unroll
  for (int fm = 0; fm < 2; ++fm)
#pragma unroll
    for (int fn = 0; fn < 4; ++fn) acc[fm][fn] = f32x4{0.f, 0.f, 0.f, 0.f};
  {
    const short* bS = W2T + (size_t)brow0 * 256 + bcol;
    for (int k0 = 0; k0 < 256; k0 += 64) {
#pragma unroll
      for (int c = 0; c < 4; ++c)
        gld16(bS + (size_t)(c * 8) * 256 + k0, bD + c * 8 * 64);
      __syncthreads();   // fences Hs writes (k0==0) and Bs staging
#pragma unroll
      for (int ks = 0; ks < 2; ++ks) {
        int sl = ks ? sl1 : sl0;
        short8v af[2], bf[4];
#pragma unroll
        for (int i = 0; i < 2; ++i)
          af[i] = *reinterpret_cast<const short8v*>(
              &Hs[(wr * 32 + i * 16 + lr) * 264 + k0 + ks * 32 + kb * 8]);
#pragma unroll
        for (int j = 0; j < 4; ++j)
          bf[j] = *reinterpret_cast<const short8v*>(
              &Bs[(wc * 64 + j * 16 + lr) * 64 + sl]);
#pragma unroll
        for (int i = 0; i < 2; ++i)
#pragma unroll
          for (int j = 0; j < 4; ++j)
            acc[i][j] = __builtin_amdgcn_mfma_f32_16x16x32_bf16(
                af[i], bf[j], acc[i][j], 0, 0, 0);
      }
      __syncthreads();
    }
  }

  float bb[4];
#pragma unroll
  for (int fn = 0; fn < 4; ++fn) bb[fn] = b2[wc * 64 + fn * 16 + lr];

  float* lns = (float*)As;           // [64][4] sums
  float* lnq = lns + 256;            // [64][4] sumsq
  float mean_[2][4], rs_[2][4];
#pragma unroll
  for (int fm = 0; fm < 2; ++fm)
#pragma unroll
    for (int i = 0; i < 4; ++i) {
      int lrow = wr * 32 + fm * 16 + kb * 4 + i;
      int r = bm + lrow;
      bool ok = r < M_TOK;
      float s = 0.f, q = 0.f;
#pragma unroll
      for (int fn = 0; fn < 4; ++fn) {
        int c = wc * 64 + fn * 16 + lr;
        float v = acc[fm][fn][i] + bb[fn];
        if (ok) v += bf2f(resid[(size_t)r * 256 + c]);
        acc[fm][fn][i] = v;
        s += v; q += v * v;
      }
#pragma unroll
      for (int o = 1; o < 16; o <<= 1) {
        s += __shfl_xor(s, o);
        q += __shfl_xor(q, o);
      }
      if (lr == 0) { lns[lrow * 4 + wc] = s; lnq[lrow * 4 + wc] = q; }
    }
  __syncthreads();
#pragma unroll
  for (int fm = 0; fm < 2; ++fm)
#pragma unroll
    for (int i = 0; i < 4; ++i) {
      int lrow = wr * 32 + fm * 16 + kb * 4 + i;
      float S = lns[lrow * 4 + 0] + lns[lrow * 4 + 1] + lns[lrow * 4 + 2] +
                lns[lrow * 4 + 3];
      float Q = lnq[lrow * 4 + 0] + lnq[lrow * 4 + 1] + lnq[lrow * 4 + 2] +
                lnq[lrow * 4 + 3];
      float mean = S * (1.f / 256.f);
      float var = Q * (1.f / 256.f) - mean * mean;
      mean_[fm][i] = mean;
      rs_[fm][i] = rsqrtf(var + 1e-5f);
    }
  float g4[4], lb4[4];
#pragma unroll
  for (int fn = 0; fn < 4; ++fn) {
    int c = wc * 64 + fn * 16 + lr;
    g4[fn] = g[c]; lb4[fn] = lnb[c];
  }
#pragma unroll
  for (int fm = 0; fm < 2; ++fm)
#pragma unroll
    for (int i = 0; i < 4; ++i) {
      int r = bm + wr * 32 + fm * 16 + kb * 4 + i;
      if (r >= M_TOK) continue;
#pragma unroll
      for (int fn = 0; fn < 4; ++fn) {
        int c = wc * 64 + fn * 16 + lr;
        float o = (acc[fm][fn][i] - mean_[fm][i]) * rs_[fm][i] * g4[fn] + lb4[fn];
        if (MODE == 3) {
          outf[(size_t)r * 256 + c] = o;
        } else {
          resid[(size_t)r * 256 + c] = f2bf(o);
          qb[(size_t)r * 256 + c] = f2bf(o + bf2f(posb[(size_t)r * 256 + c]));
        }
      }
    }
}

// ---------------------------------------------------------------------------
// Deformable sampling + fused softmax, bf16 value/attn. (unchanged)
// 256 thr = 8 tokens x 32 lanes; bijective XCD swizzle over 2500 blocks.
// ---------------------------------------------------------------------------
__global__ __launch_bounds__(256) void sample_kernel(
    const short* __restrict__ value, const float* __restrict__ offaw,
    short* __restrict__ attn) {
  __shared__ float loff[8][64];
  __shared__ float lw[8][32];
  int bid = blockIdx.x;
  int xcd = bid & 7, idx = bid >> 3;
  int swz = (xcd < 4 ? xcd * 313 : 4 * 313 + (xcd - 4) * 312) + idx;
  int tok0 = swz * 8;
  int tid = threadIdx.x;
  for (int i = tid; i < 768; i += 256) {
    int t = i / 96, j = i - t * 96;
    float v = offaw[(size_t)(tok0 + t) * 96 + j];
    if (j < 64) loff[t][j] = v; else lw[t][j - 64] = v;
  }
  __syncthreads();
  if (tid < 64) {                                   // softmax over 4 points
    int t = tid >> 3, h = tid & 7;
    float* w = &lw[t][h * 4];
    float m = fmaxf(fmaxf(w[0], w[1]), fmaxf(w[2], w[3]));
    float e0 = __expf(w[0] - m), e1 = __expf(w[1] - m);
    float e2 = __expf(w[2] - m), e3 = __expf(w[3] - m);
    float inv = 1.f / (e0 + e1 + e2 + e3);
    w[0] = e0 * inv; w[1] = e1 * inv; w[2] = e2 * inv; w[3] = e3 * inv;
  }
  __syncthreads();

  int ts = tid >> 5, lane = tid & 31;
  int token = tok0 + ts;
  int h = lane >> 2, d8 = (lane & 3) * 8;
  int b = token / S_TOK;
  int s = token - b * S_TOK;
  int ix = s % WID, iy = s / WID;
  const short* vbase = value + ((size_t)b * S_TOK) * D_MODEL + h * DH + d8;

  float acc[8] = {};
#pragma unroll
  for (int p = 0; p < N_POINTS; ++p) {
    float ox = loff[ts][h * 8 + p * 2 + 0];
    float oy = loff[ts][h * 8 + p * 2 + 1];
    float aw = lw[ts][h * 4 + p];
    float px = (float)ix + ox;
    float py = (float)iy + oy;
    float x0f = floorf(px), y0f = floorf(py);
    int x0 = (int)x0f, y0 = (int)y0f;
    float wx1 = px - x0f, wx0 = 1.f - wx1;
    float wy1 = py - y0f, wy0 = 1.f - wy1;
    float sv[8] = {};
    bool xa = (x0 >= 0) & (x0 < WID), xb = (x0 + 1 >= 0) & (x0 + 1 < WID);
    bool ya = (y0 >= 0) & (y0 < HGT), yb = (y0 + 1 >= 0) & (y0 + 1 < HGT);
#define CORNER(XOK, YOK, XI, YI, WGT)                                        \
    if ((XOK) & (YOK)) {                                                     \
      short8v v = *reinterpret_cast<const short8v*>(                         \
          vbase + (size_t)((YI) * WID + (XI)) * D_MODEL);                    \
      float wg = (WGT);                                                      \
      _Pragma("unroll")                                                      \
      for (int j = 0; j < 8; ++j) sv[j] = fmaf(wg, bf2f(v[j]), sv[j]);       \
    }
    CORNER(xa, ya, x0, y0, wx0 * wy0)
    CORNER(xb, ya, x0 + 1, y0, wx1 * wy0)
    CORNER(xa, yb, x0, y0 + 1, wx0 * wy1)
    CORNER(xb, yb, x0 + 1, y0 + 1, wx1 * wy1)
#undef CORNER
#pragma unroll
    for (int j = 0; j < 8; ++j) acc[j] = fmaf(aw, sv[j], acc[j]);
  }
  short8v o;
#pragma unroll
  for (int j = 0; j < 8; ++j) o[j] = f2bf(acc[j]);
  *reinterpret_cast<short8v*>(attn + (size_t)token * D_MODEL + h * DH + d8) = o;
}

// ---------------------------------------------------------------------------
extern "C" void kernel_launch(void* const* d_in, const int* in_sizes, int n_in,
                              void* d_out, int out_size, void* d_ws,
                              size_t ws_size, hipStream_t stream) {
  const float* features  = (const float*)d_in[0];
  const float* pos_embed = (const float*)d_in[1];
  const float* level_emb = (const float*)d_in[2];
  const float* off_w = (const float*)d_in[3];
  const float* off_b = (const float*)d_in[4];
  const float* aw_w  = (const float*)d_in[5];
  const float* aw_b  = (const float*)d_in[6];
  const float* val_w = (const float*)d_in[7];
  const float* val_b = (const float*)d_in[8];
  const float* out_w = (const float*)d_in[9];
  const float* out_b = (const float*)d_in[10];
  const float* ln1_g = (const float*)d_in[11];
  const float* ln1_b = (const float*)d_in[12];
  const float* ffn_w1 = (const float*)d_in[13];
  const float* ffn_b1 = (const float*)d_in[14];
  const float* ffn_w2 = (const float*)d_in[15];
  const float* ffn_b2 = (const float*)d_in[16];
  const float* ln3_g = (const float*)d_in[17];
  const float* ln3_b = (const float*)d_in[18];

  float* ws = (float*)d_ws;
  const size_t BIG = (size_t)M_TOK * D_MODEL;  // 5.12M elems
  float* offaw = ws;                           // [M,96]  f32
  short* posb  = (short*)(offaw + (size_t)M_TOK * 96);  // [M,256] bf16
  short* srcb  = posb + BIG;                   // [M,256] bf16 (residual state)
  short* qb    = srcb + BIG;                   // [M,256] bf16
  short* value = qb + BIG;                     // [M,256] bf16
  short* attn  = value + BIG;                  // [M,256] bf16
  short* wv  = attn + BIG;                     // [6][256][256] bf16 (swz W^T)
  short* wo  = wv + (size_t)6 * 65536;
  short* w1t = wo + (size_t)6 * 65536;
  short* w2t = w1t + (size_t)6 * 65536;
  short* woa = w2t + (size_t)6 * 65536;        // [6][128][256] bf16 (padded)
  float* bias96 = (float*)(woa + (size_t)6 * 32768);  // [6][96]

  prep_tokens<<<dim3(313, 8, 2), dim3(32, 8), 0, stream>>>(
      features, pos_embed, level_emb, posb, srcb, qb);
  prep_weights<<<dim3(8, 8, 36), dim3(32, 8), 0, stream>>>(
      val_w, out_w, ffn_w1, ffn_w2, off_w, aw_w, wv, wo, w1t, w2t, woa);
  biascat_kernel<<<dim3(6), dim3(96), 0, stream>>>(off_b, aw_b, bias96);

  for (int l = 0; l < N_LAYERS; ++l) {
    const short* wvl = wv + (size_t)l * 65536;
    const short* wol = wo + (size_t)l * 65536;
    const short* w1l = w1t + (size_t)l * 65536;
    const short* w2l = w2t + (size_t)l * 65536;
    const short* woal = woa + (size_t)l * 32768;

    // value projection (blocks 0..312) + offsets/logits (313..625)
    gemm_vq<<<626, 512, 0, stream>>>(srcb, qb, wvl, woal,
                                     val_b + (size_t)l * 256,
                                     bias96 + (size_t)l * 96, value, offaw);
    // deformable sampling -> attn bf16
    sample_kernel<<<M_TOK / 8, 256, 0, stream>>>(value, offaw, attn);
    // out-proj + residual + LN1 -> srcb (in-place)
    gemm_out_ln1<<<313, 512, 0, stream>>>(
        attn, wol, out_b + (size_t)l * 256, srcb,
        ln1_g + (size_t)l * 256, ln1_b + (size_t)l * 256);
    // fused FFN1+FFN2 + residual + LN3 -> srcb/qb (last: d_out f32)
    if (l == N_LAYERS - 1) {
      gemm_ffn_ln3<3><<<313, 512, 0, stream>>>(
          srcb, w1l, ffn_b1 + (size_t)l * 256, w2l, ffn_b2 + (size_t)l * 256,
          srcb, (float*)d_out, nullptr, nullptr,
          ln3_g + (size_t)l * 256, ln3_b + (size_t)l * 256);
    } else {
      gemm_ffn_ln3<2><<<313, 512, 0, stream>>>(
          srcb, w1l, ffn_b1 + (size_t)l * 256, w2l, ffn_b2 + (size_t)l * 256,
          srcb, nullptr, qb, posb,
          ln3_g + (size_t)l * 256, ln3_b + (size_t)l * 256);
    }
  }
}

// Round 24
// 440.700 us; speedup vs baseline: 1.0304x; 1.0304x over previous
//
#include <hip/hip_runtime.h>
#include <math.h>

#define HGT 100
#define WID 100
#define S_TOK (HGT * WID)          // 10000
#define D_MODEL 256
#define N_HEADS 8
#define DH 32
#define N_POINTS 4
#define N_LAYERS 6
#define BS 2
#define M_TOK (BS * S_TOK)         // 20000

typedef __attribute__((ext_vector_type(8))) short short8v;   // 8 bf16 = 16 B
typedef __attribute__((ext_vector_type(4))) short short4v;   // 4 bf16 = 8 B
typedef __attribute__((ext_vector_type(4))) float f32x4;

__device__ __forceinline__ short f2bf(float f) {
  union { float f; unsigned u; } v; v.f = f;
  unsigned r = v.u + 0x7fff + ((v.u >> 16) & 1);   // round-to-nearest-even
  return (short)(r >> 16);
}
__device__ __forceinline__ float bf2f(short s) {
  union { unsigned u; float f; } v;
  v.u = ((unsigned)(unsigned short)s) << 16;
  return v.f;
}

// async global -> LDS, 16 B per lane. lds dest = wave-uniform base + lane*16.
__device__ __forceinline__ void gld16(const short* g, short* l) {
  __builtin_amdgcn_global_load_lds(
      (const __attribute__((address_space(1))) unsigned int*)g,
      (__attribute__((address_space(3))) unsigned int*)l, 16, 0, 0);
}

// ---------------------------------------------------------------------------
// Fused token prep: transpose [bs,C,S]->[bs,S,C] for features AND pos; emit
// posb bf16 (pos+level), srcb bf16(features), qb bf16(src+posb).
// grid (313, 8, 2) block (32,8)
// ---------------------------------------------------------------------------
__global__ __launch_bounds__(256) void prep_tokens(
    const float* __restrict__ feat, const float* __restrict__ posin,
    const float* __restrict__ level, short* __restrict__ posb,
    short* __restrict__ srcb, short* __restrict__ qb) {
  __shared__ float tf[32][33];
  __shared__ float tp[32][33];
  int b = blockIdx.z;
  int s0 = blockIdx.x * 32;
  int c0 = blockIdx.y * 32;
  int tx = threadIdx.x, ty = threadIdx.y;
#pragma unroll
  for (int i = 0; i < 4; ++i) {
    int c = c0 + ty + i * 8;
    int s = s0 + tx;
    bool ok = s < S_TOK;
    size_t o = ((size_t)b * D_MODEL + c) * S_TOK + s;
    tf[ty + i * 8][tx] = ok ? feat[o] : 0.f;
    tp[ty + i * 8][tx] = ok ? posin[o] : 0.f;
  }
  __syncthreads();
#pragma unroll
  for (int i = 0; i < 4; ++i) {
    int s = s0 + ty + i * 8;
    int c = c0 + tx;
    if (s < S_TOK) {
      float f = tf[tx][ty + i * 8];
      float p = tp[tx][ty + i * 8] + level[c];
      size_t o = ((size_t)b * S_TOK + s) * D_MODEL + c;
      short pb = f2bf(p);
      posb[o] = pb;
      srcb[o] = f2bf(f);
      qb[o] = f2bf(f + bf2f(pb));
    }
  }
}

// ---------------------------------------------------------------------------
// Fused weight prep: transpose + fp32->bf16 + XOR pre-swizzle.
// Dst element (n, k) stored at col (k&~63) | ((((k>>3)&7) ^ (n&7))<<3) | (k&7)
// so that a LINEAR 16B/lane copy into LDS yields LDS(row,s)=logical(row,
// s^(row&7)).  grid (8, 8, 36): z = l*6+widx; widx 0..3: 256-col weights;
// 4: off (64 rows of woa); 5: aw (rows 64..95 of woa; woa padded to 128).
// ---------------------------------------------------------------------------
__global__ __launch_bounds__(256) void prep_weights(
    const float* __restrict__ val_w, const float* __restrict__ out_w,
    const float* __restrict__ ffn_w1, const float* __restrict__ ffn_w2,
    const float* __restrict__ off_w, const float* __restrict__ aw_w,
    short* __restrict__ wv, short* __restrict__ wo, short* __restrict__ w1t,
    short* __restrict__ w2t, short* __restrict__ woa) {
  int z = blockIdx.z;
  int l = z / 6, widx = z - (z / 6) * 6;
  const float* s;
  short* d;
  int N;
  if (widx == 0)      { s = val_w  + (size_t)l * 65536; d = wv  + (size_t)l * 65536; N = 256; }
  else if (widx == 1) { s = out_w  + (size_t)l * 65536; d = wo  + (size_t)l * 65536; N = 256; }
  else if (widx == 2) { s = ffn_w1 + (size_t)l * 65536; d = w1t + (size_t)l * 65536; N = 256; }
  else if (widx == 3) { s = ffn_w2 + (size_t)l * 65536; d = w2t + (size_t)l * 65536; N = 256; }
  else if (widx == 4) { s = off_w + (size_t)l * 256 * 64; d = woa + (size_t)l * 32768; N = 64; }
  else                { s = aw_w  + (size_t)l * 256 * 32; d = woa + (size_t)l * 32768 + (size_t)64 * 256; N = 32; }
  int n0 = blockIdx.x * 32, k0 = blockIdx.y * 32;
  if (n0 >= N) return;
  __shared__ float t[32][33];
  int tx = threadIdx.x, ty = threadIdx.y;
#pragma unroll
  for (int i = 0; i < 4; ++i) {
    int k = k0 + ty + i * 8;
    int n = n0 + tx;
    t[ty + i * 8][tx] = (n < N) ? s[(size_t)k * N + n] : 0.f;
  }
  __syncthreads();
#pragma unroll
  for (int i = 0; i < 4; ++i) {
    int n = n0 + ty + i * 8;
    int k = k0 + tx;
    if (n < N) {
      int slot = ((k >> 3) & 7) ^ (n & 7);   // (64+n)&7 == n&7 for widx5
      size_t dk = (size_t)(k & ~63) + (slot << 3) + (k & 7);
      d[(size_t)n * 256 + dk] = f2bf(t[tx][ty + i * 8]);
    }
  }
}

__global__ void biascat_kernel(const float* __restrict__ ob,
                               const float* __restrict__ ab,
                               float* __restrict__ dst) {
  int l = blockIdx.x, i = threadIdx.x;
  dst[l * 96 + i] = (i < 64) ? ob[l * 64 + i] : ab[l * 32 + (i - 64)];
}

// ---------------------------------------------------------------------------
// Merged value-proj + offset/logit GEMM dispatch. Grid 626 x 512 thr.
// Blocks 0..312  (role A): value = bf16(srcb@WV^T + vb)     [N=256]
// Blocks 313..625 (role B): offaw = f32(qb@WOA^T + bias96)  [N=96; woa 128r]
// gload_lds staging; LDS unpadded [row][64] with XOR-swizzled slots.
// ---------------------------------------------------------------------------
__global__ __launch_bounds__(512) void gemm_vq(
    const short* __restrict__ srcb, const short* __restrict__ qb,
    const short* __restrict__ WV, const short* __restrict__ WOA,
    const float* __restrict__ vb, const float* __restrict__ b96,
    short* __restrict__ value, float* __restrict__ offaw) {
  __shared__ __align__(16) short As[64 * 64];
  __shared__ __align__(16) short Bs[256 * 64];
  int tid = threadIdx.x;
  int wave = tid >> 6, lane = tid & 63;
  int lr = lane & 15, kb = lane >> 4;
  int bx = blockIdx.x;
  int sc16 = (lane & 7) ^ ((lane >> 3) & 7);   // A source slot involution
  int r7 = lr & 7;
  int sl0 = (kb ^ r7) << 3;                    // ks=0 read slot*8
  int sl1 = ((4 + kb) ^ r7) << 3;              // ks=1

  if (bx < 313) {
    // ---------------- role A: value projection (N=256) ----------------
    int wr = wave >> 2, wc = wave & 3;
    int bm = bx * 64;
    int arow = bm + wave * 8 + (lane >> 3);
    if (arow >= M_TOK) arow = M_TOK - 1;       // tail rows discarded later
    const short* aS = srcb + (size_t)arow * 256 + sc16 * 8;
    short* aD = As + wave * 512;
    const short* bS = WV + (size_t)(wave * 32 + (lane >> 3)) * 256 + (lane & 7) * 8;
    short* bD = Bs + wave * 32 * 64;

    f32x4 acc[2][4] = {};
    for (int k0 = 0; k0 < 256; k0 += 64) {
      gld16(aS + k0, aD);
#pragma unroll
      for (int c = 0; c < 4; ++c)
        gld16(bS + (size_t)(c * 8) * 256 + k0, bD + c * 8 * 64);
      __syncthreads();
#pragma unroll
      for (int ks = 0; ks < 2; ++ks) {
        int sl = ks ? sl1 : sl0;
        short8v af[2], bf[4];
#pragma unroll
        for (int i = 0; i < 2; ++i)
          af[i] = *reinterpret_cast<const short8v*>(
              &As[(wr * 32 + i * 16 + lr) * 64 + sl]);
#pragma unroll
        for (int j = 0; j < 4; ++j)
          bf[j] = *reinterpret_cast<const short8v*>(
              &Bs[(wc * 64 + j * 16 + lr) * 64 + sl]);
#pragma unroll
        for (int i = 0; i < 2; ++i)
#pragma unroll
          for (int j = 0; j < 4; ++j)
            acc[i][j] = __builtin_amdgcn_mfma_f32_16x16x32_bf16(
                af[i], bf[j], acc[i][j], 0, 0, 0);
      }
      __syncthreads();
    }
    float bb[4];
#pragma unroll
    for (int fn = 0; fn < 4; ++fn) bb[fn] = vb[wc * 64 + fn * 16 + lr];
#pragma unroll
    for (int fm = 0; fm < 2; ++fm)
#pragma unroll
      for (int i = 0; i < 4; ++i) {
        int r = bm + wr * 32 + fm * 16 + kb * 4 + i;
        if (r >= M_TOK) continue;
#pragma unroll
        for (int fn = 0; fn < 4; ++fn) {
          int c = wc * 64 + fn * 16 + lr;
          value[(size_t)r * 256 + c] = f2bf(acc[fm][fn][i] + bb[fn]);
        }
      }
  } else {
    // ---------------- role B: offsets + logits (N=96, 128 staged) ------
    int wr = wave >> 2, wc = wave & 3;         // 2 x 4 waves, tile 32x32
    int bm = (bx - 313) * 64;
    int arow = bm + wave * 8 + (lane >> 3);
    if (arow >= M_TOK) arow = M_TOK - 1;
    const short* aS = qb + (size_t)arow * 256 + sc16 * 8;
    short* aD = As + wave * 512;
    const short* bS = WOA + (size_t)(wave * 16 + (lane >> 3)) * 256 + (lane & 7) * 8;
    short* bD = Bs + wave * 16 * 64;

    f32x4 acc[2][2] = {};
    for (int k0 = 0; k0 < 256; k0 += 64) {
      gld16(aS + k0, aD);
#pragma unroll
      for (int c = 0; c < 2; ++c)
        gld16(bS + (size_t)(c * 8) * 256 + k0, bD + c * 8 * 64);
      __syncthreads();
#pragma unroll
      for (int ks = 0; ks < 2; ++ks) {
        int sl = ks ? sl1 : sl0;
        short8v af[2], bf[2];
#pragma unroll
        for (int i = 0; i < 2; ++i)
          af[i] = *reinterpret_cast<const short8v*>(
              &As[(wr * 32 + i * 16 + lr) * 64 + sl]);
#pragma unroll
        for (int j = 0; j < 2; ++j)
          bf[j] = *reinterpret_cast<const short8v*>(
              &Bs[(wc * 32 + j * 16 + lr) * 64 + sl]);
#pragma unroll
        for (int i = 0; i < 2; ++i)
#pragma unroll
          for (int j = 0; j < 2; ++j)
            acc[i][j] = __builtin_amdgcn_mfma_f32_16x16x32_bf16(
                af[i], bf[j], acc[i][j], 0, 0, 0);
      }
      __syncthreads();
    }
#pragma unroll
    for (int fn = 0; fn < 2; ++fn) {
      int c = wc * 32 + fn * 16 + lr;
      if (c >= 96) continue;
      float bv = b96[c];
#pragma unroll
      for (int fm = 0; fm < 2; ++fm)
#pragma unroll
        for (int i = 0; i < 4; ++i) {
          int r = bm + wr * 32 + fm * 16 + kb * 4 + i;
          if (r < M_TOK) offaw[(size_t)r * 96 + c] = acc[fm][fn][i] + bv;
        }
    }
  }
}

// ---------------------------------------------------------------------------
// Out-proj + residual + LN1. BM=64, 512 thr = 8 waves (2x4), wave 32x64.
// Grid 313. gload_lds staging, XOR-swizzled LDS. resid in-place (bf16).
// ---------------------------------------------------------------------------
__global__ __launch_bounds__(512) void gemm_out_ln1(
    const short* __restrict__ A, const short* __restrict__ WT,
    const float* __restrict__ bias, short* __restrict__ resid,
    const float* __restrict__ g, const float* __restrict__ lnb) {
  __shared__ __align__(16) short As[64 * 64];
  __shared__ __align__(16) short Bs[256 * 64];
  int tid = threadIdx.x;
  int wave = tid >> 6, lane = tid & 63;
  int lr = lane & 15, kb = lane >> 4;
  int wr = wave >> 2, wc = wave & 3;
  int bm = blockIdx.x * 64;
  int sc16 = (lane & 7) ^ ((lane >> 3) & 7);
  int r7 = lr & 7;
  int sl0 = (kb ^ r7) << 3;
  int sl1 = ((4 + kb) ^ r7) << 3;

  int arow = bm + wave * 8 + (lane >> 3);
  if (arow >= M_TOK) arow = M_TOK - 1;
  const short* aS = A + (size_t)arow * 256 + sc16 * 8;
  short* aD = As + wave * 512;
  const short* bS = WT + (size_t)(wave * 32 + (lane >> 3)) * 256 + (lane & 7) * 8;
  short* bD = Bs + wave * 32 * 64;

  f32x4 acc[2][4] = {};

  for (int k0 = 0; k0 < 256; k0 += 64) {
    gld16(aS + k0, aD);
#pragma unroll
    for (int c = 0; c < 4; ++c)
      gld16(bS + (size_t)(c * 8) * 256 + k0, bD + c * 8 * 64);
    __syncthreads();
#pragma unroll
    for (int ks = 0; ks < 2; ++ks) {
      int sl = ks ? sl1 : sl0;
      short8v af[2], bf[4];
#pragma unroll
      for (int i = 0; i < 2; ++i)
        af[i] = *reinterpret_cast<const short8v*>(
            &As[(wr * 32 + i * 16 + lr) * 64 + sl]);
#pragma unroll
      for (int j = 0; j < 4; ++j)
        bf[j] = *reinterpret_cast<const short8v*>(
            &Bs[(wc * 64 + j * 16 + lr) * 64 + sl]);
#pragma unroll
      for (int i = 0; i < 2; ++i)
#pragma unroll
        for (int j = 0; j < 4; ++j)
          acc[i][j] = __builtin_amdgcn_mfma_f32_16x16x32_bf16(af[i], bf[j],
                                                              acc[i][j], 0, 0, 0);
    }
    __syncthreads();
  }

  float bb[4];
#pragma unroll
  for (int fn = 0; fn < 4; ++fn) bb[fn] = bias[wc * 64 + fn * 16 + lr];

  // ---- fused residual (bf16) + LayerNorm epilogue ----
  float* lns = (float*)As;           // [64][4] row partial sums
  float* lnq = lns + 256;            // [64][4] row partial sumsq
  float mean_[2][4], rs_[2][4];
#pragma unroll
  for (int fm = 0; fm < 2; ++fm)
#pragma unroll
    for (int i = 0; i < 4; ++i) {
      int lrow = wr * 32 + fm * 16 + kb * 4 + i;
      int r = bm + lrow;
      bool ok = r < M_TOK;
      float s = 0.f, q = 0.f;
#pragma unroll
      for (int fn = 0; fn < 4; ++fn) {
        int c = wc * 64 + fn * 16 + lr;
        float v = acc[fm][fn][i] + bb[fn];
        if (ok) v += bf2f(resid[(size_t)r * 256 + c]);
        acc[fm][fn][i] = v;
        s += v; q += v * v;
      }
#pragma unroll
      for (int o = 1; o < 16; o <<= 1) {
        s += __shfl_xor(s, o);
        q += __shfl_xor(q, o);
      }
      if (lr == 0) { lns[lrow * 4 + wc] = s; lnq[lrow * 4 + wc] = q; }
    }
  __syncthreads();
#pragma unroll
  for (int fm = 0; fm < 2; ++fm)
#pragma unroll
    for (int i = 0; i < 4; ++i) {
      int lrow = wr * 32 + fm * 16 + kb * 4 + i;
      float S = lns[lrow * 4 + 0] + lns[lrow * 4 + 1] + lns[lrow * 4 + 2] +
                lns[lrow * 4 + 3];
      float Q = lnq[lrow * 4 + 0] + lnq[lrow * 4 + 1] + lnq[lrow * 4 + 2] +
                lnq[lrow * 4 + 3];
      float mean = S * (1.f / 256.f);
      float var = Q * (1.f / 256.f) - mean * mean;
      mean_[fm][i] = mean;
      rs_[fm][i] = rsqrtf(var + 1e-5f);
    }
  float g4[4], lb4[4];
#pragma unroll
  for (int fn = 0; fn < 4; ++fn) {
    int c = wc * 64 + fn * 16 + lr;
    g4[fn] = g[c]; lb4[fn] = lnb[c];
  }
#pragma unroll
  for (int fm = 0; fm < 2; ++fm)
#pragma unroll
    for (int i = 0; i < 4; ++i) {
      int r = bm + wr * 32 + fm * 16 + kb * 4 + i;
      if (r >= M_TOK) continue;
#pragma unroll
      for (int fn = 0; fn < 4; ++fn) {
        int c = wc * 64 + fn * 16 + lr;
        float o = (acc[fm][fn][i] - mean_[fm][i]) * rs_[fm][i] * g4[fn] + lb4[fn];
        resid[(size_t)r * 256 + c] = f2bf(o);
      }
    }
}

// ---------------------------------------------------------------------------
// Fused FFN: H = relu(A@W1^T+b1) in LDS, then LN(resid + H@W2^T+b2).
// gload_lds for A and both weight tiles; Hs keeps padded (264) layout.
// BM=64, 512 thr = 8 waves (2x4), wave tile 32x64. Grid: 313.
// MODE 2: -> resid bf16 in-place + qb = bf16(out+posb).
// MODE 3: -> outf f32 only (final layer).
// ---------------------------------------------------------------------------
template <int MODE>
__global__ __launch_bounds__(512) void gemm_ffn_ln3(
    const short* __restrict__ A, const short* __restrict__ W1T,
    const float* __restrict__ b1, const short* __restrict__ W2T,
    const float* __restrict__ b2, short* __restrict__ resid,
    float* __restrict__ outf, short* __restrict__ qb,
    const short* __restrict__ posb, const float* __restrict__ g,
    const float* __restrict__ lnb) {
  __shared__ __align__(16) short As[64 * 64];
  __shared__ __align__(16) short Bs[256 * 64];
  __shared__ __align__(16) short Hs[64 * 264];   // hidden, pad 264
  int tid = threadIdx.x;
  int wave = tid >> 6, lane = tid & 63;
  int lr = lane & 15, kb = lane >> 4;
  int wr = wave >> 2, wc = wave & 3;
  int bm = blockIdx.x * 64;
  int sc16 = (lane & 7) ^ ((lane >> 3) & 7);
  int r7 = lr & 7;
  int sl0 = (kb ^ r7) << 3;
  int sl1 = ((4 + kb) ^ r7) << 3;

  int arow = bm + wave * 8 + (lane >> 3);
  if (arow >= M_TOK) arow = M_TOK - 1;
  const short* aS = A + (size_t)arow * 256 + sc16 * 8;
  short* aD = As + wave * 512;
  short* bD = Bs + wave * 32 * 64;
  int brow0 = wave * 32 + (lane >> 3);
  int bcol = (lane & 7) * 8;

  f32x4 acc[2][4] = {};

  // ---- phase 1: H = relu(A@W1^T + b1) ----
  {
    const short* bS = W1T + (size_t)brow0 * 256 + bcol;
    for (int k0 = 0; k0 < 256; k0 += 64) {
      gld16(aS + k0, aD);
#pragma unroll
      for (int c = 0; c < 4; ++c)
        gld16(bS + (size_t)(c * 8) * 256 + k0, bD + c * 8 * 64);
      __syncthreads();
#pragma unroll
      for (int ks = 0; ks < 2; ++ks) {
        int sl = ks ? sl1 : sl0;
        short8v af[2], bf[4];
#pragma unroll
        for (int i = 0; i < 2; ++i)
          af[i] = *reinterpret_cast<const short8v*>(
              &As[(wr * 32 + i * 16 + lr) * 64 + sl]);
#pragma unroll
        for (int j = 0; j < 4; ++j)
          bf[j] = *reinterpret_cast<const short8v*>(
              &Bs[(wc * 64 + j * 16 + lr) * 64 + sl]);
#pragma unroll
        for (int i = 0; i < 2; ++i)
#pragma unroll
          for (int j = 0; j < 4; ++j)
            acc[i][j] = __builtin_amdgcn_mfma_f32_16x16x32_bf16(
                af[i], bf[j], acc[i][j], 0, 0, 0);
      }
      __syncthreads();
    }
    float bb1[4];
#pragma unroll
    for (int fn = 0; fn < 4; ++fn) bb1[fn] = b1[wc * 64 + fn * 16 + lr];
#pragma unroll
    for (int fm = 0; fm < 2; ++fm)
#pragma unroll
      for (int i = 0; i < 4; ++i) {
        int lrow = wr * 32 + fm * 16 + kb * 4 + i;
#pragma unroll
        for (int fn = 0; fn < 4; ++fn) {
          int c = wc * 64 + fn * 16 + lr;
          float v = fmaxf(acc[fm][fn][i] + bb1[fn], 0.f);
          Hs[lrow * 264 + c] = f2bf(v);
        }
      }
  }

  // ---- phase 2: LN(resid + H@W2^T + b2); A from Hs (plain layout) ----
#pragma unroll
  for (int fm = 0; fm < 2; ++fm)
#pragma unroll
    for (int fn = 0; fn < 4; ++fn) acc[fm][fn] = f32x4{0.f, 0.f, 0.f, 0.f};
  {
    const short* bS = W2T + (size_t)brow0 * 256 + bcol;
    for (int k0 = 0; k0 < 256; k0 += 64) {
#pragma unroll
      for (int c = 0; c < 4; ++c)
        gld16(bS + (size_t)(c * 8) * 256 + k0, bD + c * 8 * 64);
      __syncthreads();   // fences Hs writes (k0==0) and Bs staging
#pragma unroll
      for (int ks = 0; ks < 2; ++ks) {
        int sl = ks ? sl1 : sl0;
        short8v af[2], bf[4];
#pragma unroll
        for (int i = 0; i < 2; ++i)
          af[i] = *reinterpret_cast<const short8v*>(
              &Hs[(wr * 32 + i * 16 + lr) * 264 + k0 + ks * 32 + kb * 8]);
#pragma unroll
        for (int j = 0; j < 4; ++j)
          bf[j] = *reinterpret_cast<const short8v*>(
              &Bs[(wc * 64 + j * 16 + lr) * 64 + sl]);
#pragma unroll
        for (int i = 0; i < 2; ++i)
#pragma unroll
          for (int j = 0; j < 4; ++j)
            acc[i][j] = __builtin_amdgcn_mfma_f32_16x16x32_bf16(
                af[i], bf[j], acc[i][j], 0, 0, 0);
      }
      __syncthreads();
    }
  }

  float bb[4];
#pragma unroll
  for (int fn = 0; fn < 4; ++fn) bb[fn] = b2[wc * 64 + fn * 16 + lr];

  float* lns = (float*)As;           // [64][4] sums
  float* lnq = lns + 256;            // [64][4] sumsq
  float mean_[2][4], rs_[2][4];
#pragma unroll
  for (int fm = 0; fm < 2; ++fm)
#pragma unroll
    for (int i = 0; i < 4; ++i) {
      int lrow = wr * 32 + fm * 16 + kb * 4 + i;
      int r = bm + lrow;
      bool ok = r < M_TOK;
      float s = 0.f, q = 0.f;
#pragma unroll
      for (int fn = 0; fn < 4; ++fn) {
        int c = wc * 64 + fn * 16 + lr;
        float v = acc[fm][fn][i] + bb[fn];
        if (ok) v += bf2f(resid[(size_t)r * 256 + c]);
        acc[fm][fn][i] = v;
        s += v; q += v * v;
      }
#pragma unroll
      for (int o = 1; o < 16; o <<= 1) {
        s += __shfl_xor(s, o);
        q += __shfl_xor(q, o);
      }
      if (lr == 0) { lns[lrow * 4 + wc] = s; lnq[lrow * 4 + wc] = q; }
    }
  __syncthreads();
#pragma unroll
  for (int fm = 0; fm < 2; ++fm)
#pragma unroll
    for (int i = 0; i < 4; ++i) {
      int lrow = wr * 32 + fm * 16 + kb * 4 + i;
      float S = lns[lrow * 4 + 0] + lns[lrow * 4 + 1] + lns[lrow * 4 + 2] +
                lns[lrow * 4 + 3];
      float Q = lnq[lrow * 4 + 0] + lnq[lrow * 4 + 1] + lnq[lrow * 4 + 2] +
                lnq[lrow * 4 + 3];
      float mean = S * (1.f / 256.f);
      float var = Q * (1.f / 256.f) - mean * mean;
      mean_[fm][i] = mean;
      rs_[fm][i] = rsqrtf(var + 1e-5f);
    }
  float g4[4], lb4[4];
#pragma unroll
  for (int fn = 0; fn < 4; ++fn) {
    int c = wc * 64 + fn * 16 + lr;
    g4[fn] = g[c]; lb4[fn] = lnb[c];
  }
#pragma unroll
  for (int fm = 0; fm < 2; ++fm)
#pragma unroll
    for (int i = 0; i < 4; ++i) {
      int r = bm + wr * 32 + fm * 16 + kb * 4 + i;
      if (r >= M_TOK) continue;
#pragma unroll
      for (int fn = 0; fn < 4; ++fn) {
        int c = wc * 64 + fn * 16 + lr;
        float o = (acc[fm][fn][i] - mean_[fm][i]) * rs_[fm][i] * g4[fn] + lb4[fn];
        if (MODE == 3) {
          outf[(size_t)r * 256 + c] = o;
        } else {
          resid[(size_t)r * 256 + c] = f2bf(o);
          qb[(size_t)r * 256 + c] = f2bf(o + bf2f(posb[(size_t)r * 256 + c]));
        }
      }
    }
}

// ---------------------------------------------------------------------------
// Deformable sampling + fused softmax, bf16 value/attn. (unchanged)
// 256 thr = 8 tokens x 32 lanes; bijective XCD swizzle over 2500 blocks.
// ---------------------------------------------------------------------------
__global__ __launch_bounds__(256) void sample_kernel(
    const short* __restrict__ value, const float* __restrict__ offaw,
    short* __restrict__ attn) {
  __shared__ float loff[8][64];
  __shared__ float lw[8][32];
  int bid = blockIdx.x;
  int xcd = bid & 7, idx = bid >> 3;
  int swz = (xcd < 4 ? xcd * 313 : 4 * 313 + (xcd - 4) * 312) + idx;
  int tok0 = swz * 8;
  int tid = threadIdx.x;
  for (int i = tid; i < 768; i += 256) {
    int t = i / 96, j = i - t * 96;
    float v = offaw[(size_t)(tok0 + t) * 96 + j];
    if (j < 64) loff[t][j] = v; else lw[t][j - 64] = v;
  }
  __syncthreads();
  if (tid < 64) {                                   // softmax over 4 points
    int t = tid >> 3, h = tid & 7;
    float* w = &lw[t][h * 4];
    float m = fmaxf(fmaxf(w[0], w[1]), fmaxf(w[2], w[3]));
    float e0 = __expf(w[0] - m), e1 = __expf(w[1] - m);
    float e2 = __expf(w[2] - m), e3 = __expf(w[3] - m);
    float inv = 1.f / (e0 + e1 + e2 + e3);
    w[0] = e0 * inv; w[1] = e1 * inv; w[2] = e2 * inv; w[3] = e3 * inv;
  }
  __syncthreads();

  int ts = tid >> 5, lane = tid & 31;
  int token = tok0 + ts;
  int h = lane >> 2, d8 = (lane & 3) * 8;
  int b = token / S_TOK;
  int s = token - b * S_TOK;
  int ix = s % WID, iy = s / WID;
  const short* vbase = value + ((size_t)b * S_TOK) * D_MODEL + h * DH + d8;

  float acc[8] = {};
#pragma unroll
  for (int p = 0; p < N_POINTS; ++p) {
    float ox = loff[ts][h * 8 + p * 2 + 0];
    float oy = loff[ts][h * 8 + p * 2 + 1];
    float aw = lw[ts][h * 4 + p];
    float px = (float)ix + ox;
    float py = (float)iy + oy;
    float x0f = floorf(px), y0f = floorf(py);
    int x0 = (int)x0f, y0 = (int)y0f;
    float wx1 = px - x0f, wx0 = 1.f - wx1;
    float wy1 = py - y0f, wy0 = 1.f - wy1;
    float sv[8] = {};
    bool xa = (x0 >= 0) & (x0 < WID), xb = (x0 + 1 >= 0) & (x0 + 1 < WID);
    bool ya = (y0 >= 0) & (y0 < HGT), yb = (y0 + 1 >= 0) & (y0 + 1 < HGT);
#define CORNER(XOK, YOK, XI, YI, WGT)                                        \
    if ((XOK) & (YOK)) {                                                     \
      short8v v = *reinterpret_cast<const short8v*>(                         \
          vbase + (size_t)((YI) * WID + (XI)) * D_MODEL);                    \
      float wg = (WGT);                                                      \
      _Pragma("unroll")                                                      \
      for (int j = 0; j < 8; ++j) sv[j] = fmaf(wg, bf2f(v[j]), sv[j]);       \
    }
    CORNER(xa, ya, x0, y0, wx0 * wy0)
    CORNER(xb, ya, x0 + 1, y0, wx1 * wy0)
    CORNER(xa, yb, x0, y0 + 1, wx0 * wy1)
    CORNER(xb, yb, x0 + 1, y0 + 1, wx1 * wy1)
#undef CORNER
#pragma unroll
    for (int j = 0; j < 8; ++j) acc[j] = fmaf(aw, sv[j], acc[j]);
  }
  short8v o;
#pragma unroll
  for (int j = 0; j < 8; ++j) o[j] = f2bf(acc[j]);
  *reinterpret_cast<short8v*>(attn + (size_t)token * D_MODEL + h * DH + d8) = o;
}

// ---------------------------------------------------------------------------
extern "C" void kernel_launch(void* const* d_in, const int* in_sizes, int n_in,
                              void* d_out, int out_size, void* d_ws,
                              size_t ws_size, hipStream_t stream) {
  const float* features  = (const float*)d_in[0];
  const float* pos_embed = (const float*)d_in[1];
  const float* level_emb = (const float*)d_in[2];
  const float* off_w = (const float*)d_in[3];
  const float* off_b = (const float*)d_in[4];
  const float* aw_w  = (const float*)d_in[5];
  const float* aw_b  = (const float*)d_in[6];
  const float* val_w = (const float*)d_in[7];
  const float* val_b = (const float*)d_in[8];
  const float* out_w = (const float*)d_in[9];
  const float* out_b = (const float*)d_in[10];
  const float* ln1_g = (const float*)d_in[11];
  const float* ln1_b = (const float*)d_in[12];
  const float* ffn_w1 = (const float*)d_in[13];
  const float* ffn_b1 = (const float*)d_in[14];
  const float* ffn_w2 = (const float*)d_in[15];
  const float* ffn_b2 = (const float*)d_in[16];
  const float* ln3_g = (const float*)d_in[17];
  const float* ln3_b = (const float*)d_in[18];

  float* ws = (float*)d_ws;
  const size_t BIG = (size_t)M_TOK * D_MODEL;  // 5.12M elems
  float* offaw = ws;                           // [M,96]  f32
  short* posb  = (short*)(offaw + (size_t)M_TOK * 96);  // [M,256] bf16
  short* srcb  = posb + BIG;                   // [M,256] bf16 (residual state)
  short* qb    = srcb + BIG;                   // [M,256] bf16
  short* value = qb + BIG;                     // [M,256] bf16
  short* attn  = value + BIG;                  // [M,256] bf16
  short* wv  = attn + BIG;                     // [6][256][256] bf16 (swz W^T)
  short* wo  = wv + (size_t)6 * 65536;
  short* w1t = wo + (size_t)6 * 65536;
  short* w2t = w1t + (size_t)6 * 65536;
  short* woa = w2t + (size_t)6 * 65536;        // [6][128][256] bf16 (padded)
  float* bias96 = (float*)(woa + (size_t)6 * 32768);  // [6][96]

  prep_tokens<<<dim3(313, 8, 2), dim3(32, 8), 0, stream>>>(
      features, pos_embed, level_emb, posb, srcb, qb);
  prep_weights<<<dim3(8, 8, 36), dim3(32, 8), 0, stream>>>(
      val_w, out_w, ffn_w1, ffn_w2, off_w, aw_w, wv, wo, w1t, w2t, woa);
  biascat_kernel<<<dim3(6), dim3(96), 0, stream>>>(off_b, aw_b, bias96);

  for (int l = 0; l < N_LAYERS; ++l) {
    const short* wvl = wv + (size_t)l * 65536;
    const short* wol = wo + (size_t)l * 65536;
    const short* w1l = w1t + (size_t)l * 65536;
    const short* w2l = w2t + (size_t)l * 65536;
    const short* woal = woa + (size_t)l * 32768;

    // value projection (blocks 0..312) + offsets/logits (313..625)
    gemm_vq<<<626, 512, 0, stream>>>(srcb, qb, wvl, woal,
                                     val_b + (size_t)l * 256,
                                     bias96 + (size_t)l * 96, value, offaw);
    // deformable sampling -> attn bf16
    sample_kernel<<<M_TOK / 8, 256, 0, stream>>>(value, offaw, attn);
    // out-proj + residual + LN1 -> srcb (in-place)
    gemm_out_ln1<<<313, 512, 0, stream>>>(
        attn, wol, out_b + (size_t)l * 256, srcb,
        ln1_g + (size_t)l * 256, ln1_b + (size_t)l * 256);
    // fused FFN1+FFN2 + residual + LN3 -> srcb/qb (last: d_out f32)
    if (l == N_LAYERS - 1) {
      gemm_ffn_ln3<3><<<313, 512, 0, stream>>>(
          srcb, w1l, ffn_b1 + (size_t)l * 256, w2l, ffn_b2 + (size_t)l * 256,
          srcb, (float*)d_out, nullptr, nullptr,
          ln3_g + (size_t)l * 256, ln3_b + (size_t)l * 256);
    } else {
      gemm_ffn_ln3<2><<<313, 512, 0, stream>>>(
          srcb, w1l, ffn_b1 + (size_t)l * 256, w2l, ffn_b2 + (size_t)l * 256,
          srcb, nullptr, qb, posb,
          ln3_g + (size_t)l * 256, ln3_b + (size_t)l * 256);
    }
  }
}